// Round 3
// baseline (2359.856 us; speedup 1.0000x reference)
//
#include <hip/hip_runtime.h>
#include <math.h>

#define BB 32
#define CC 3
#define HH 224
#define WW 224
#define HWS (HH*WW)            // 50176
#define NELEM (BB*CC*HWS)      // 4,816,896
#define NTAPS (9*HWS)          // 451,584
#define EPS_IN 1e-5f
#define LNUM 10

#define TS 16
#define HALO 4
#define TR (TS + 2*HALO)          // 24 rows/cols incl halo
#define RSTRIDE (TR*8 + 4)        // 196 floats; +16B pad rotates banks by 4/row
#define CSTRIDE (TR*RSTRIDE)      // 4704 floats per channel
#define NTILES ((HH/TS)*(WW/TS))  // 196
#define NBLK (NTILES*4)           // 784 blocks (4 batch-groups of 8)

__device__ __forceinline__ float fast_tanh(float z) {
    z = fminf(fmaxf(z, -15.f), 15.f);
    float e = __expf(2.f * z);
#if __has_builtin(__builtin_amdgcn_rcpf)
    return (e - 1.f) * __builtin_amdgcn_rcpf(e + 1.f);
#else
    return (e - 1.f) / (e + 1.f);
#endif
}

// ---------------- zero stats ----------------
__global__ void zero_kernel(float* __restrict__ p, int n) {
    int i = blockIdx.x * 256 + threadIdx.x;
    if (i < n) p[i] = 0.f;
}

// ---------------- precompute taps: (y0,x0) short2 + (wy,wx) float2 --------
__global__ __launch_bounds__(256) void taps_kernel(
    const float* __restrict__ off,   // [18,H,W] batch-0 offset plane
    short2* __restrict__ tsi, float2* __restrict__ tsw)
{
    int gid = blockIdx.x * 256 + threadIdx.x;    // k*HWS + pix, grid exact
    int k = gid / HWS, pix = gid - k * HWS;
    int h = pix / WW, wc = pix - h * WW;
    int ky = k / 3, kx = k - 3 * ky;
    float dy = off[(2 * k)     * HWS + pix];
    float dx = off[(2 * k + 1) * HWS + pix];
    float py = (float)(h  + ky - 1) + dy;
    float px = (float)(wc + kx - 1) + dx;
    float y0f = floorf(py), x0f = floorf(px);
    short2 si;
    si.x = (short)(int)y0f;
    si.y = (short)(int)x0f;
    float2 sw;
    sw.x = py - y0f;
    sw.y = px - x0f;
    tsi[gid] = si; tsw[gid] = sw;
}

// ---------------- transpose [B,C,H,W] -> [C,HW,B] ----------------
__global__ __launch_bounds__(256) void transpose_in_kernel(
    const float* __restrict__ x, float* __restrict__ xT)
{
    __shared__ float tile[64][33];
    int bid = blockIdx.x;
    int c = bid / (HWS / 64);
    int pix0 = (bid % (HWS / 64)) * 64;
    int t = threadIdx.x;
    int i = t & 63, brow = t >> 6;
    #pragma unroll
    for (int jj = 0; jj < 8; ++jj) {
        int b = brow + jj * 4;
        tile[i][b] = x[((size_t)(b * 3 + c)) * HWS + pix0 + i];
    }
    __syncthreads();
    int b2 = t & 31, irow = t >> 5;
    #pragma unroll
    for (int j = 0; j < 8; ++j) {
        int i2 = irow + j * 8;
        xT[((size_t)(c * HWS + pix0 + i2)) * 32 + b2] = tile[i2][b2];
    }
}

// ---------------- fused: (norm+tanh of prev) -> deform conv -> stats ------
// Block = 16x16 pixel tile x 8 batch images. Threads 512: bq = t&1 (batch
// quad within the 8), pxl = t>>1 (pixel in tile).
__global__ __launch_bounds__(512, 4) void conv_tile_kernel(
    const float* __restrict__ prev,   // [C,HW,B] raw previous activations
    const short2* __restrict__ tsi,   // [9,HW] (y0,x0)
    const float2* __restrict__ tsw,   // [9,HW] (wy,wx)
    const float* __restrict__ wt,     // [3,3,9]
    const float* __restrict__ statsPrev, // [B*3][2] of previous iter
    const float* __restrict__ gamma, const float* __restrict__ beta,
    int donorm,
    float* __restrict__ yT,           // [C,HW,B] raw conv output
    float* __restrict__ statsOut)     // [B*3][2] accumulators (this iter)
{
    __shared__ float lds[3 * CSTRIDE];              // 56448 B
    __shared__ float w_s[81];
    __shared__ float red[8][2][24];

    int t = threadIdx.x;
    int p = blockIdx.x;
    int logical = (p & 7) * (NBLK / 8) + (p >> 3);  // XCD-contiguous mapping
    int tile = logical >> 2;
    int bg   = logical & 3;                          // batch group (8 images)
    int tileY0 = (tile / (WW / TS)) * TS;
    int tileX0 = (tile % (WW / TS)) * TS;

    int bq  = t & 1;                                 // batch quad within group
    int pxl = t >> 1;                                // 0..255
    int py  = pxl >> 4, px = pxl & 15;
    int bofs = bg * 8 + bq * 4;                      // first of my 4 batches

    if (t < 81) w_s[t] = wt[t];

    // ---- per-thread affine params for my 4 batches x 3 channels ----
    float4 mm[3], gg[3];
    float bt3[3];
    #pragma unroll
    for (int c = 0; c < 3; ++c) {
        bt3[c] = beta[c];
        float4 m4, g4;
        if (donorm) {
            float gc = gamma[c];
            #pragma unroll
            for (int j = 0; j < 4; ++j) {
                int b = bofs + j;
                float s = statsPrev[(b * 3 + c) * 2 + 0];
                float q = statsPrev[(b * 3 + c) * 2 + 1];
                float mean = s * (1.f / HWS);
                float var  = fmaxf(q * (1.f / HWS) - mean * mean, 0.f);
                ((float*)&m4)[j] = mean;
                ((float*)&g4)[j] = gc * rsqrtf(var + EPS_IN);
            }
        } else {
            m4 = make_float4(0.f, 0.f, 0.f, 0.f);
            g4 = make_float4(1.f, 1.f, 1.f, 1.f);
        }
        mm[c] = m4; gg[c] = g4;
    }

    // ---- stage tile+halo into LDS, applying norm+tanh on the fly ----
    #pragma unroll
    for (int i = 0; i < 7; ++i) {
        int cell = i * 256 + pxl;
        if (cell < 3 * TR * TR) {
            int c  = cell / (TR * TR);
            int r  = cell - c * (TR * TR);
            int ly = r / TR, lx = r - ly * TR;
            int gy = min(max(tileY0 - HALO + ly, 0), HH - 1);
            int gx = min(max(tileX0 - HALO + lx, 0), WW - 1);
            float4 v = *(const float4*)(prev + ((size_t)(c * HWS + gy * WW + gx)) * 32 + bofs);
            if (donorm) {
                float4 M = (c == 0) ? mm[0] : ((c == 1) ? mm[1] : mm[2]);
                float4 G = (c == 0) ? gg[0] : ((c == 1) ? gg[1] : gg[2]);
                float  Bt = (c == 0) ? bt3[0] : ((c == 1) ? bt3[1] : bt3[2]);
                v.x = fast_tanh((v.x - M.x) * G.x + Bt);
                v.y = fast_tanh((v.y - M.y) * G.y + Bt);
                v.z = fast_tanh((v.z - M.z) * G.z + Bt);
                v.w = fast_tanh((v.w - M.w) * G.w + Bt);
            }
            *(float4*)&lds[c * CSTRIDE + ly * RSTRIDE + lx * 8 + bq * 4] = v;
        }
    }
    __syncthreads();

    // ---- main: 9 taps x 3 in-ch x 4 corners, gathered from LDS ----
    int gp = (tileY0 + py) * WW + (tileX0 + px);     // my output pixel
    float4 a0 = make_float4(0.f, 0.f, 0.f, 0.f), a1 = a0, a2 = a0;
    int bq4 = bq * 4;

    #pragma unroll 3
    for (int k = 0; k < 9; ++k) {
        short2 si = tsi[k * HWS + gp];
        float2 sw = tsw[k * HWS + gp];
        int y0 = si.x, x0 = si.y;
        int y1 = y0 + 1, x1 = x0 + 1;
        float wy = sw.x, wx = sw.y;
        float wy0 = (y0 >= 0 && y0 < HH) ? (1.f - wy) : 0.f;
        float wy1 = (y1 >= 0 && y1 < HH) ? wy : 0.f;
        float wx0 = (x0 >= 0 && x0 < WW) ? (1.f - wx) : 0.f;
        float wx1 = (x1 >= 0 && x1 < WW) ? wx : 0.f;
        float w00 = wy0 * wx0, w01 = wy0 * wx1, w10 = wy1 * wx0, w11 = wy1 * wx1;
        int cy0 = min(max(y0, 0), HH - 1), cy1 = min(max(y1, 0), HH - 1);
        int cx0 = min(max(x0, 0), WW - 1), cx1 = min(max(x1, 0), WW - 1);
        int ly0 = cy0 - tileY0 + HALO, ly1 = cy1 - tileY0 + HALO;
        int lx0 = cx0 - tileX0 + HALO, lx1 = cx1 - tileX0 + HALO;
        bool intile = (ly0 >= 0) & (ly1 < TR) & (lx0 >= 0) & (lx1 < TR);
        int i00 = ly0 * RSTRIDE + lx0 * 8 + bq4;
        int i01 = ly0 * RSTRIDE + lx1 * 8 + bq4;
        int i10 = ly1 * RSTRIDE + lx0 * 8 + bq4;
        int i11 = ly1 * RSTRIDE + lx1 * 8 + bq4;

        #pragma unroll
        for (int c = 0; c < 3; ++c) {
            float4 v00, v01, v10, v11;
            if (intile) {
                const float* L = lds + c * CSTRIDE;
                v00 = *(const float4*)(L + i00);
                v01 = *(const float4*)(L + i01);
                v10 = *(const float4*)(L + i10);
                v11 = *(const float4*)(L + i11);
            } else {
                const float* P = prev + (size_t)c * HWS * 32 + bofs;
                v00 = *(const float4*)(P + (size_t)(cy0 * WW + cx0) * 32);
                v01 = *(const float4*)(P + (size_t)(cy0 * WW + cx1) * 32);
                v10 = *(const float4*)(P + (size_t)(cy1 * WW + cx0) * 32);
                v11 = *(const float4*)(P + (size_t)(cy1 * WW + cx1) * 32);
                if (donorm) {
                    float4 M = (c == 0) ? mm[0] : ((c == 1) ? mm[1] : mm[2]);
                    float4 G = (c == 0) ? gg[0] : ((c == 1) ? gg[1] : gg[2]);
                    float  Bt = (c == 0) ? bt3[0] : ((c == 1) ? bt3[1] : bt3[2]);
                    #define NRM(v) do { \
                        v.x = fast_tanh((v.x - M.x) * G.x + Bt); \
                        v.y = fast_tanh((v.y - M.y) * G.y + Bt); \
                        v.z = fast_tanh((v.z - M.z) * G.z + Bt); \
                        v.w = fast_tanh((v.w - M.w) * G.w + Bt); } while (0)
                    NRM(v00); NRM(v01); NRM(v10); NRM(v11);
                    #undef NRM
                }
            }
            float4 s;
            s.x = v00.x * w00 + v01.x * w01 + v10.x * w10 + v11.x * w11;
            s.y = v00.y * w00 + v01.y * w01 + v10.y * w10 + v11.y * w11;
            s.z = v00.z * w00 + v01.z * w01 + v10.z * w10 + v11.z * w11;
            s.w = v00.w * w00 + v01.w * w01 + v10.w * w10 + v11.w * w11;
            float wo0 = w_s[c * 9 + k], wo1 = w_s[27 + c * 9 + k], wo2 = w_s[54 + c * 9 + k];
            a0.x = fmaf(s.x, wo0, a0.x); a0.y = fmaf(s.y, wo0, a0.y);
            a0.z = fmaf(s.z, wo0, a0.z); a0.w = fmaf(s.w, wo0, a0.w);
            a1.x = fmaf(s.x, wo1, a1.x); a1.y = fmaf(s.y, wo1, a1.y);
            a1.z = fmaf(s.z, wo1, a1.z); a1.w = fmaf(s.w, wo1, a1.w);
            a2.x = fmaf(s.x, wo2, a2.x); a2.y = fmaf(s.y, wo2, a2.y);
            a2.z = fmaf(s.z, wo2, a2.z); a2.w = fmaf(s.w, wo2, a2.w);
        }
    }

    // ---- store raw conv output, coalesced ----
    float* yb = yT + (size_t)gp * 32 + bofs;
    *(float4*)(yb)                        = a0;
    *(float4*)(yb + (size_t)HWS * 32)     = a1;
    *(float4*)(yb + (size_t)2 * HWS * 32) = a2;

    // ---- per-(b,c) sum/sumsq: reduce over the 256 pixels ----
    float v[24];
    #pragma unroll
    for (int j = 0; j < 4; ++j) {
        float e0 = ((float*)&a0)[j], e1 = ((float*)&a1)[j], e2 = ((float*)&a2)[j];
        v[0*8 + j*2 + 0] = e0; v[0*8 + j*2 + 1] = e0 * e0;
        v[1*8 + j*2 + 0] = e1; v[1*8 + j*2 + 1] = e1 * e1;
        v[2*8 + j*2 + 0] = e2; v[2*8 + j*2 + 1] = e2 * e2;
    }
    #pragma unroll
    for (int j = 0; j < 24; ++j) {
        #pragma unroll
        for (int o = 2; o <= 32; o <<= 1)          // pixels are lane-stride 2
            v[j] += __shfl_xor(v[j], o);
    }
    int lane = t & 63, wv = t >> 6;
    if (lane < 2) {
        #pragma unroll
        for (int j = 0; j < 24; ++j) red[wv][lane][j] = v[j];
    }
    __syncthreads();
    if (t < 48) {
        int bq2 = t / 24, j = t % 24;
        float sum = 0.f;
        #pragma unroll
        for (int w2 = 0; w2 < 8; ++w2) sum += red[w2][bq2][j];
        int c = j >> 3, comp = (j >> 1) & 3, which = j & 1;
        int b = bg * 8 + bq2 * 4 + comp;
        atomicAdd(&statsOut[(b * 3 + c) * 2 + which], sum);
    }
}

// ---------------- final: norm + tanh + transpose back to [B,C,H,W] --------
__global__ __launch_bounds__(256) void norm_final_kernel(
    const float* __restrict__ y, const float* __restrict__ stats,
    const float* __restrict__ gamma, const float* __restrict__ beta,
    float* __restrict__ out)
{
    __shared__ float tile[64][33];
    int bid = blockIdx.x;
    int c = bid / (HWS / 64);
    int pix0 = (bid % (HWS / 64)) * 64;
    int t = threadIdx.x;
    int b = t & 31;
    float s  = stats[(b * 3 + c) * 2 + 0];
    float qq = stats[(b * 3 + c) * 2 + 1];
    float mean = s * (1.f / HWS);
    float var  = fmaxf(qq * (1.f / HWS) - mean * mean, 0.f);
    float inv  = rsqrtf(var + EPS_IN);
    float g = gamma[c] * inv, bt = beta[c];
    int irow = t >> 5;
    #pragma unroll
    for (int j = 0; j < 8; ++j) {
        int i = irow + j * 8;
        float v = y[((size_t)(c * HWS + pix0 + i)) * 32 + b];
        tile[i][b] = fast_tanh((v - mean) * g + bt);
    }
    __syncthreads();
    int i2 = t & 63, brow = t >> 6;
    #pragma unroll
    for (int jj = 0; jj < 8; ++jj) {
        int b2 = brow + jj * 4;
        out[((size_t)(b2 * 3 + c)) * HWS + pix0 + i2] = tile[i2][b2];
    }
}

extern "C" void kernel_launch(void* const* d_in, const int* in_sizes, int n_in,
                              void* d_out, int out_size, void* d_ws, size_t ws_size,
                              hipStream_t stream) {
    const float* x     = (const float*)d_in[0];
    const float* wt    = (const float*)d_in[1];
    const float* off   = (const float*)d_in[2];   // batch-tiled -> plane 0
    const float* gamma = (const float*)d_in[3];
    const float* beta  = (const float*)d_in[4];

    float* out  = (float*)d_out;
    float* bufA = (float*)d_ws;
    float* bufB = bufA + NELEM;
    short2* tsi = (short2*)(bufB + NELEM);
    float2* tsw = (float2*)((char*)tsi + (size_t)NTAPS * sizeof(short2));
    float* stats = (float*)((char*)tsw + (size_t)NTAPS * sizeof(float2));
    // ws: 2*19.27MB + 1.8MB + 3.6MB + 7.7KB ~= 44 MB

    zero_kernel<<<(LNUM * 192 + 255) / 256, 256, 0, stream>>>(stats, LNUM * 192);
    taps_kernel<<<NTAPS / 256, 256, 0, stream>>>(off, tsi, tsw);
    transpose_in_kernel<<<3 * (HWS / 64), 256, 0, stream>>>(x, bufA);

    float* cur = bufA;
    float* nxt = bufB;
    for (int it = 0; it < LNUM; ++it) {
        const float* stPrev = (it == 0) ? stats : stats + (it - 1) * 192;
        float* stOut = stats + it * 192;
        conv_tile_kernel<<<NBLK, 512, 0, stream>>>(
            cur, tsi, tsw, wt, stPrev, gamma, beta, (it > 0) ? 1 : 0, nxt, stOut);
        float* tmp = cur; cur = nxt; nxt = tmp;
    }
    // after 10 convs the last raw output is in `cur` (bufA), stats slice 9
    norm_final_kernel<<<3 * (HWS / 64), 256, 0, stream>>>(
        cur, stats + 9 * 192, gamma, beta, out);
}

// Round 4
// 733.745 us; speedup vs baseline: 3.2162x; 3.2162x over previous
//
#include <hip/hip_runtime.h>
#include <math.h>

#define BB 32
#define CC 3
#define HH 224
#define WW 224
#define HWS (HH*WW)            // 50176
#define NELEM (BB*CC*HWS)      // 4,816,896
#define NTAPS (9*HWS)          // 451,584
#define EPS_IN 1e-5f
#define LNUM 10

#define NBLK_CONV (BB*HWS/256)   // 6272
#define NBLK_NORM (NELEM/1024)   // 4704

__device__ __forceinline__ float fast_tanh(float z) {
    z = fminf(fmaxf(z, -15.f), 15.f);
    float e = __expf(2.f * z);
    return (e - 1.f) * __frcp_rn(e + 1.f);
}

// ---------------- zero stats ----------------
__global__ void zero_kernel(float* __restrict__ p, int n) {
    int i = blockIdx.x * 256 + threadIdx.x;
    if (i < n) p[i] = 0.f;
}

// ------- precompute expanded taps: clamped flat idx + masked weights ------
__global__ __launch_bounds__(256) void taps_kernel(
    const float* __restrict__ off,   // [18,H,W] batch-0 offset plane
    int4* __restrict__ ti, float4* __restrict__ tw)
{
    int gid = blockIdx.x * 256 + threadIdx.x;    // k*HWS + pix, grid exact
    int k = gid / HWS, pix = gid - k * HWS;
    int h = pix / WW, wc = pix - h * WW;
    int ky = k / 3, kx = k - 3 * ky;
    float dy = off[(2 * k)     * HWS + pix];
    float dx = off[(2 * k + 1) * HWS + pix];
    float py = (float)(h  + ky - 1) + dy;
    float px = (float)(wc + kx - 1) + dx;
    float y0f = floorf(py), x0f = floorf(px);
    float wy = py - y0f, wx = px - x0f;
    int iy0 = (int)y0f, ix0 = (int)x0f;
    int iy1 = iy0 + 1,  ix1 = ix0 + 1;
    float vy0 = (iy0 >= 0 && iy0 < HH) ? 1.f : 0.f;
    float vy1 = (iy1 >= 0 && iy1 < HH) ? 1.f : 0.f;
    float vx0 = (ix0 >= 0 && ix0 < WW) ? 1.f : 0.f;
    float vx1 = (ix1 >= 0 && ix1 < WW) ? 1.f : 0.f;
    int cy0 = min(max(iy0, 0), HH - 1), cy1 = min(max(iy1, 0), HH - 1);
    int cx0 = min(max(ix0, 0), WW - 1), cx1 = min(max(ix1, 0), WW - 1);
    int4 ii;
    ii.x = cy0 * WW + cx0; ii.y = cy0 * WW + cx1;
    ii.z = cy1 * WW + cx0; ii.w = cy1 * WW + cx1;
    float4 ww;
    ww.x = (1.f - wy) * (1.f - wx) * vy0 * vx0;
    ww.y = (1.f - wy) * wx         * vy0 * vx1;
    ww.z = wy         * (1.f - wx) * vy1 * vx0;
    ww.w = wy         * wx         * vy1 * vx1;
    ti[gid] = ii; tw[gid] = ww;
}

// ---------------- deformable conv (+stats), [B,C,H,W] layout ----------------
// One thread = one (b,h,w) pixel, all 3 out channels. Blocks XCD-swizzled so
// each XCD owns a contiguous pixel range across all 32 batches (tap + x slice
// ~L2-resident; producer XCD in iter i == consumer XCD in iter i+1).
__global__ __launch_bounds__(256) void conv_kernel(
    const float* __restrict__ x,     // [B,C,H,W]
    const int4*  __restrict__ ti,    // [9,HW]
    const float4* __restrict__ tw,   // [9,HW]
    const float* __restrict__ wt,    // [3,3,9]
    float* __restrict__ y,           // [B,C,H,W]
    float* __restrict__ stats)       // [B*3][2]
{
    __shared__ float w_s[81];
    int t = threadIdx.x;
    if (t < 81) w_s[t] = wt[t];
    __syncthreads();

    int p = blockIdx.x;
    int logical = (p & 7) * (NBLK_CONV / 8) + (p >> 3);
    int b     = logical & 31;
    int chunk = logical >> 5;            // 0..195
    int pix   = chunk * 256 + t;

    const float* xb = x + b * (CC * HWS);
    float acc0 = 0.f, acc1 = 0.f, acc2 = 0.f;

    #pragma unroll 3
    for (int k = 0; k < 9; ++k) {
        int4   ii = ti[k * HWS + pix];
        float4 ww = tw[k * HWS + pix];
        #pragma unroll
        for (int c = 0; c < 3; ++c) {
            const float* xc = xb + c * HWS;
            float v00 = xc[ii.x];
            float v01 = xc[ii.y];
            float v10 = xc[ii.z];
            float v11 = xc[ii.w];
            float s = v00 * ww.x + v01 * ww.y + v10 * ww.z + v11 * ww.w;
            acc0 = fmaf(s, w_s[ 0 + c * 9 + k], acc0);
            acc1 = fmaf(s, w_s[27 + c * 9 + k], acc1);
            acc2 = fmaf(s, w_s[54 + c * 9 + k], acc2);
        }
    }

    float* yb = y + b * (CC * HWS) + pix;
    yb[0]       = acc0;
    yb[HWS]     = acc1;
    yb[2 * HWS] = acc2;

    // ---- per-(b,channel) sum / sumsq reduction ----
    float s0 = acc0, q0 = acc0 * acc0;
    float s1 = acc1, q1 = acc1 * acc1;
    float s2 = acc2, q2 = acc2 * acc2;
    #pragma unroll
    for (int o = 32; o > 0; o >>= 1) {
        s0 += __shfl_down(s0, o); q0 += __shfl_down(q0, o);
        s1 += __shfl_down(s1, o); q1 += __shfl_down(q1, o);
        s2 += __shfl_down(s2, o); q2 += __shfl_down(q2, o);
    }
    __shared__ float red[4][6];
    int wave = t >> 6, lane = t & 63;
    if (lane == 0) {
        red[wave][0] = s0; red[wave][1] = q0;
        red[wave][2] = s1; red[wave][3] = q1;
        red[wave][4] = s2; red[wave][5] = q2;
    }
    __syncthreads();
    if (t < 6) {
        float v = red[0][t] + red[1][t] + red[2][t] + red[3][t];
        int ch = t >> 1, which = t & 1;
        atomicAdd(&stats[(b * 3 + ch) * 2 + which], v);
    }
}

// ------------- instance norm + tanh, float4, swizzled like conv -----------
__global__ __launch_bounds__(256) void norm_kernel(
    const float* __restrict__ y, float* __restrict__ out,
    const float* __restrict__ stats,
    const float* __restrict__ gamma, const float* __restrict__ beta)
{
    int q = blockIdx.x;
    int logical = (q & 7) * (NBLK_NORM / 8) + (q >> 3);
    int pc = logical / 96;               // 1024-elem pixel chunk, 0..48
    int bc = logical - pc * 96;          // b*3+c
    int c  = bc % 3;
    float s  = stats[bc * 2 + 0];
    float qq = stats[bc * 2 + 1];
    float mean = s * (1.f / HWS);
    float var  = fmaxf(qq * (1.f / HWS) - mean * mean, 0.f);
    float g  = gamma[c] * rsqrtf(var + EPS_IN);
    float bt = beta[c];
    size_t base = (size_t)bc * HWS + pc * 1024 + threadIdx.x * 4;
    float4 v = *(const float4*)(y + base);
    v.x = fast_tanh((v.x - mean) * g + bt);
    v.y = fast_tanh((v.y - mean) * g + bt);
    v.z = fast_tanh((v.z - mean) * g + bt);
    v.w = fast_tanh((v.w - mean) * g + bt);
    *(float4*)(out + base) = v;
}

extern "C" void kernel_launch(void* const* d_in, const int* in_sizes, int n_in,
                              void* d_out, int out_size, void* d_ws, size_t ws_size,
                              hipStream_t stream) {
    const float* x     = (const float*)d_in[0];
    const float* wt    = (const float*)d_in[1];
    const float* off   = (const float*)d_in[2];   // batch-tiled -> plane 0
    const float* gamma = (const float*)d_in[3];
    const float* beta  = (const float*)d_in[4];

    float* out  = (float*)d_out;
    float* bufA = (float*)d_ws;
    float* bufB = bufA + NELEM;
    int4*  ti   = (int4*)(bufB + NELEM);
    float4* tw  = (float4*)((char*)ti + (size_t)NTAPS * 16);
    float* stats = (float*)((char*)tw + (size_t)NTAPS * 16);
    // ws: 2*19.27MB + 2*7.2MB + 7.7KB ~= 53 MB

    zero_kernel<<<(LNUM * 192 + 255) / 256, 256, 0, stream>>>(stats, LNUM * 192);
    taps_kernel<<<NTAPS / 256, 256, 0, stream>>>(off, ti, tw);

    const float* cur = x;
    for (int it = 0; it < LNUM; ++it) {
        float* conv_out = (it & 1) ? bufB : bufA;
        float* st = stats + it * 192;
        conv_kernel<<<NBLK_CONV, 256, 0, stream>>>(cur, ti, tw, wt, conv_out, st);
        float* norm_dst = (it == LNUM - 1) ? out : conv_out;
        norm_kernel<<<NBLK_NORM, 256, 0, stream>>>(conv_out, norm_dst, st, gamma, beta);
        cur = norm_dst;
        if (it == LNUM - 1) break;
    }
}